// Round 24
// baseline (121.677 us; speedup 1.0000x reference)
//
#include <hip/hip_runtime.h>
#include <hip/hip_bf16.h>
#include <math.h>

#define RFL(x) __builtin_amdgcn_readfirstlane(x)

typedef short bfrag __attribute__((ext_vector_type(8)));   // 8 bf16 (4 VGPR)
typedef float ffrag __attribute__((ext_vector_type(4)));   // 4 f32 acc

// LIF: v = v + (x - v)/2 ; s = (v >= 1) ; v = s ? 0 : v   (exact rounding match)
static __device__ __forceinline__ float lif_upd(float& v, float x) {
  v = __fadd_rn(v, __fmul_rn(__fsub_rn(x, v), 0.5f));
  float s = (v >= 1.0f) ? 1.0f : 0.0f;
  v = (v >= 1.0f) ? 0.0f : v;
  return s;
}

static __device__ __forceinline__ unsigned short f2bf(float x) {
  __hip_bfloat16 h = __float2bfloat16(x);
  return *reinterpret_cast<unsigned short*>(&h);
}
static __device__ __forceinline__ float bf2f(unsigned short u) {
  __hip_bfloat16 h = *reinterpret_cast<__hip_bfloat16*>(&u);
  return __bfloat162float(h);
}

static __device__ __forceinline__ void zring(unsigned short* buf, int W2, int idx) {
  int PERIM = 4 * W2 - 4;
  int c8 = idx & 7;
  int r = idx >> 3;
  int p = r % PERIM; int pl = r / PERIM;
  int row, col;
  if (p < W2)            { row = 0;      col = p; }
  else if (p < 2 * W2)   { row = W2 - 1; col = p - W2; }
  else { int q = p - 2 * W2; row = 1 + (q >> 1); col = (q & 1) ? (W2 - 1) : 0; }
  *(uint4*)(buf + ((size_t)(pl * W2 + row) * W2 + col) * 64 + c8 * 8) =
      make_uint4(0u, 0u, 0u, 0u);
}

// One launch: weight 3-split (147,456) + halo zeroing (126,976) + x padding (1,131,520).
__global__ __launch_bounds__(256) void k_prep(
    const float* __restrict__ wc, unsigned short* __restrict__ wt,
    unsigned short* __restrict__ sp0, const float* __restrict__ x,
    float* __restrict__ padx)
{
  int id = blockIdx.x * 256 + threadIdx.x;
  if (id < 147456) {
    // weight split: wt[((l*3+s)*9+tap)*4096 + co*64 + ci]
    int tap = id % 9; int r = id / 9;
    int ci = r & 63; r >>= 6;
    int co = r & 63; int l = r >> 6;
    float w = wc[(size_t)(((l * 64 + co) * 64 + ci) * 9) + tap];
    unsigned short h0 = f2bf(w);  float r1 = __fsub_rn(w, bf2f(h0));
    unsigned short h1 = f2bf(r1); float r2 = __fsub_rn(r1, bf2f(h1));
    unsigned short h2 = f2bf(r2);
    size_t base = (size_t)((l * 3) * 9 + tap) * 4096 + co * 64 + ci;
    wt[base] = h0;
    wt[base + 9 * 4096] = h1;
    wt[base + 18 * 4096] = h2;
    return;
  }
  id -= 147456;
  if (id < 126976) {
    if (id < 66560)            zring(sp0,            66, id);
    else if (id < 100352)      zring(sp0 + 8921088,  34, id - 66560);
    else if (id < 117760)      zring(sp0 + 11288576, 18, id - 100352);
    else                       zring(sp0 + 11952128, 10, id - 117760);
    return;
  }
  id -= 126976;
  // pad x: padx[plane][130][136], interior (r=1..128, c=2..129) <- x[plane][r-1][c-2]
  if (id < 1131520) {
    int c = id % 136;
    int r = (id / 136) % 130;
    int plane = id / (136 * 130);
    float v = 0.f;
    if (r >= 1 && r <= 128 && c >= 2 && c <= 129)
      v = x[(size_t)plane * 16384 + (r - 1) * 128 + (c - 2)];
    padx[id] = v;
  }
}

// Layer 0 (known-good: WRITE == output, no spill): fused conv(2->64)+BN+LIF+2x2
// pool, padded input, co-blocked 4. Thread = 1 pooled px x 4 co. (R18 form —
// local optimum: co-block-8 x2, im2col-MFMA x2, vertical-pair x1 all regressed.)
__global__ __launch_bounds__(256, 4) void k_conv0(
    const float* __restrict__ px,  // [32][2][130][136] padded
    const float* __restrict__ w,   // [64][2][3][3]
    const float* __restrict__ bng, const float* __restrict__ bnb,
    const float* __restrict__ bnm, const float* __restrict__ bnv,
    unsigned short* __restrict__ out)
{
  int n   = RFL(blockIdx.x & 7);
  int b2  = blockIdx.x >> 3;          // [0,256)
  int cog = RFL(b2 & 15);             // 4-channel group
  int pp  = ((b2 >> 4) << 8) | threadIdx.x;   // [0,4096) pooled positions
  int py = pp >> 6, pxc = pp & 63;

  float gsc[4], bias[4];
  #pragma unroll
  for (int j = 0; j < 4; ++j) {
    int co = cog * 4 + j;
    float inv = 1.0f / sqrtf(bnv[co] + 1e-5f);
    gsc[j]  = __fmul_rn(bng[co], inv);
    bias[j] = __fsub_rn(bnb[co], __fmul_rn(__fmul_rn(bnm[co], bng[co]), inv));
  }

  float vm[4][4];
  #pragma unroll
  for (int j = 0; j < 4; ++j)
    #pragma unroll
    for (int q = 0; q < 4; ++q) vm[j][q] = 0.f;

  #pragma unroll 1
  for (int t = 0; t < 4; ++t) {
    float s[4][4];
    #pragma unroll
    for (int j = 0; j < 4; ++j)
      #pragma unroll
      for (int q = 0; q < 4; ++q) s[j][q] = 0.f;

    #pragma unroll
    for (int ci = 0; ci < 2; ++ci) {
      const float* pl = px + (size_t)((n * 4 + t) * 2 + ci) * 17680;
      float q[4][4];
      #pragma unroll
      for (int i = 0; i < 4; ++i) {
        const float* rp = pl + (2 * py + i) * 136 + 2 * pxc;
        float2 a = *(const float2*)(rp);
        float2 b = *(const float2*)(rp + 2);
        float2 c = *(const float2*)(rp + 4);
        q[i][0] = a.y; q[i][1] = b.x; q[i][2] = b.y; q[i][3] = c.x;
      }
      #pragma unroll
      for (int j = 0; j < 4; ++j) {
        const float* wp = w + (cog * 4 + j) * 18 + ci * 9;   // uniform -> s_load
        #pragma unroll
        for (int ky = 0; ky < 3; ++ky)
          #pragma unroll
          for (int kx = 0; kx < 3; ++kx) {
            float wv = wp[ky * 3 + kx];
            s[j][0] = fmaf(q[ky    ][kx    ], wv, s[j][0]);
            s[j][1] = fmaf(q[ky    ][kx + 1], wv, s[j][1]);
            s[j][2] = fmaf(q[ky + 1][kx    ], wv, s[j][2]);
            s[j][3] = fmaf(q[ky + 1][kx + 1], wv, s[j][3]);
          }
      }
    }
    ushort4 u4;
    unsigned short us[4];
    #pragma unroll
    for (int j = 0; j < 4; ++j) {
      float h0 = __fadd_rn(__fmul_rn(s[j][0], gsc[j]), bias[j]);
      float h1 = __fadd_rn(__fmul_rn(s[j][1], gsc[j]), bias[j]);
      float h2 = __fadd_rn(__fmul_rn(s[j][2], gsc[j]), bias[j]);
      float h3 = __fadd_rn(__fmul_rn(s[j][3], gsc[j]), bias[j]);
      float sp = fmaxf(fmaxf(lif_upd(vm[j][0], h0), lif_upd(vm[j][1], h1)),
                       fmaxf(lif_upd(vm[j][2], h2), lif_upd(vm[j][3], h3)));
      us[j] = (sp >= 0.5f) ? (unsigned short)0x3F80 : (unsigned short)0;
    }
    u4.x = us[0]; u4.y = us[1]; u4.z = us[2]; u4.w = us[3];
    size_t pix = (size_t)((t * 8 + n) * 66 + (py + 1)) * 66 + (pxc + 1);
    *(ushort4*)(out + pix * 64 + cog * 4) = u4;
  }
}

// MFMA conv(64->64)+BN+LIF+2x2 pool, LDS-staged & placement-agnostic.
// launch_bounds (256,4): measured VGPR 72-84 fits the 128 cap, LDS 36KB allows
// 4 blocks/CU -> the old (256,3) declaration was the binding occupancy limit.
template<int H>
__global__ __launch_bounds__(256, 4) void k_convT(
    const unsigned short* __restrict__ in,   // [32][H+2][H+2][64] padded spikes
    const unsigned short* __restrict__ wtl,  // [3][9][64][64] bf16 (this layer)
    const float* __restrict__ bng, const float* __restrict__ bnb,
    const float* __restrict__ bnm, const float* __restrict__ bnv,
    unsigned short* __restrict__ osp)        // [32][H/2+2][H/2+2][64] padded
{
  constexpr int W2 = H + 2;
  constexpr int HP2 = H / 2 + 2;
  constexpr int XT = H / 16;
  constexpr int YT = H / 2;                  // YS = 2
  constexpr int XS = 18;
  constexpr int TILE = 4 * 4 * XS * 64;      // 18432 ushorts (36 KB)
  constexpr int CHUNKS = TILE / 8;           // 2304 16B chunks

  __shared__ unsigned short tile[TILE];

  int tid = threadIdx.x;
  int lane = tid & 63;
  int cog = tid >> 6;                        // wave = cog
  int bid = blockIdx.x;
  int n  = RFL(bid & 7);
  int rest = bid >> 3;
  int xt = RFL(rest % XT);
  int yt = RFL(rest / XT);
  int x0 = xt * 16, y0 = yt * 2;
  int col = lane & 15, kg = lane >> 4;
  int co = cog * 16 + col;

  float inv = 1.0f / sqrtf(bnv[co] + 1e-5f);
  float g  = __fmul_rn(bng[co], inv);
  float bc = __fsub_rn(bnb[co], __fmul_rn(__fmul_rn(bnm[co], bng[co]), inv));

  // ---- stage all 4 timesteps: global_load_lds, LDS linear, source pre-swizzled ----
  #pragma unroll
  for (int it = 0; it < CHUNKS / 256; ++it) {
    int c = it * 256 + tid;
    int slot = c & 7;                // 16B slot within pix line
    int pix = c >> 3;                // (tt*4+row)*18 + pxl
    int pxl = pix % XS;
    int rw  = pix / XS;              // [0,16)
    int row = rw & 3, tt = rw >> 2;
    int src16 = slot ^ (pxl & 7);    // inverse swizzle (XOR involution)
    const unsigned short* s = in +
        ((size_t)(tt * 8 + n) * W2 * W2 + (size_t)(y0 + row) * W2 + (x0 + pxl)) * 64 + src16 * 8;
    __builtin_amdgcn_global_load_lds(
        (const __attribute__((address_space(1))) unsigned int*)s,
        (__attribute__((address_space(3))) unsigned int*)&tile[(it * 256 + cog * 64) * 8],
        16, 0, 0);
  }
  __syncthreads();

  // ---- MFMA: rotated (kx,kh) per wave, bv[3][3] preloaded, tp inner ----
  ffrag acc[4][2];
  #pragma unroll
  for (int tt = 0; tt < 4; ++tt)
    #pragma unroll
    for (int yy = 0; yy < 2; ++yy) {
      acc[tt][yy][0] = 0.f; acc[tt][yy][1] = 0.f;
      acc[tt][yy][2] = 0.f; acc[tt][yy][3] = 0.f;
    }

  #pragma unroll
  for (int kxi = 0; kxi < 3; ++kxi) {
    int kxr = kxi + cog;                     // wave-uniform rotation
    const int kx = (kxr >= 3) ? ((kxr >= 6) ? kxr - 6 : kxr - 3) : kxr;
    const int pxl = kx + col;
    const int swz = (pxl & 7) << 3;
    #pragma unroll
    for (int khi = 0; khi < 2; ++khi) {
      const int kh = khi ^ ((cog >> 1) & 1); // second-level phase split
      bfrag bv[3][3];                        // [ky][s] — 9 batched global loads
      #pragma unroll
      for (int ky = 0; ky < 3; ++ky)
        #pragma unroll
        for (int s = 0; s < 3; ++s)
          bv[ky][s] = *(const bfrag*)(wtl + (size_t)(s * 9 + ky * 3 + kx) * 4096 +
                                      cog * 1024 + col * 64 + kh * 32 + kg * 8);
      #pragma unroll
      for (int tp = 0; tp < 2; ++tp) {       // tt-pair: {0,1}, {2,3}
        bfrag ar[2][4];                      // [tt within pair][row 0..3]
        #pragma unroll
        for (int ti = 0; ti < 2; ++ti)
          #pragma unroll
          for (int rr = 0; rr < 4; ++rr)
            ar[ti][rr] = *(const bfrag*)&tile[(((tp * 2 + ti) * 4 + rr) * XS + pxl) * 64 +
                                              ((kh * 32 + kg * 8) ^ swz)];
        __builtin_amdgcn_s_setprio(1);
        #pragma unroll
        for (int ky = 0; ky < 3; ++ky)
          #pragma unroll
          for (int s = 0; s < 3; ++s)
            #pragma unroll
            for (int ti = 0; ti < 2; ++ti)
              #pragma unroll
              for (int yy = 0; yy < 2; ++yy)
                acc[tp * 2 + ti][yy] = __builtin_amdgcn_mfma_f32_16x16x32_bf16(
                    ar[ti][yy + ky], bv[ky][s], acc[tp * 2 + ti][yy], 0, 0, 0);
        __builtin_amdgcn_s_setprio(0);
      }
    }
  }

  // ---- BN + LIF (t-sequential) + 2x2 pool -> pack (aliased into tile) ----
  float v[2][4];
  #pragma unroll
  for (int yy = 0; yy < 2; ++yy)
    #pragma unroll
    for (int j = 0; j < 4; ++j) v[yy][j] = 0.f;

  unsigned short sp[4][2];
  #pragma unroll
  for (int tt = 0; tt < 4; ++tt) {
    float s0[4], s1[4];
    #pragma unroll
    for (int j = 0; j < 4; ++j) {
      s0[j] = lif_upd(v[0][j], __fadd_rn(__fmul_rn(acc[tt][0][j], g), bc));
      s1[j] = lif_upd(v[1][j], __fadd_rn(__fmul_rn(acc[tt][1][j], g), bc));
    }
    #pragma unroll
    for (int b2 = 0; b2 < 2; ++b2) {
      float m = fmaxf(fmaxf(s0[2 * b2], s0[2 * b2 + 1]),
                      fmaxf(s1[2 * b2], s1[2 * b2 + 1]));
      sp[tt][b2] = (m >= 0.5f) ? (unsigned short)0x3F80 : (unsigned short)0;
    }
  }
  __syncthreads();   // all waves done reading tile
  #pragma unroll
  for (int tt = 0; tt < 4; ++tt)
    #pragma unroll
    for (int b2 = 0; b2 < 2; ++b2)
      tile[(tt * 8 + kg * 2 + b2) * 64 + co] = sp[tt][b2];
  __syncthreads();

  // ---- full-line write: 256 threads = 4t x 8ppx x 8 chunks ----
  {
    int c16 = tid & 7, ppx = (tid >> 3) & 7, tt = tid >> 6;
    uint4 d = *(const uint4*)&tile[(tt * 8 + ppx) * 64 + c16 * 8];
    *(uint4*)(osp + ((size_t)((tt * 8 + n) * HP2 + (yt + 1)) * HP2 +
                     (xt * 8 + ppx + 1)) * 64 + c16 * 8) = d;
  }
}

// Layer 4 (H=8): MFMA conv + BN, t-parallel (no LIF). A row=(y_off,x). n = blockIdx&7.
__global__ __launch_bounds__(256, 2) void k_conv4M(
    const unsigned short* __restrict__ in,   // [32][10][10][64] bf16
    const unsigned short* __restrict__ wtl,  // [3][9][64][64] bf16 (layer 4)
    const float* __restrict__ bng, const float* __restrict__ bnb,
    const float* __restrict__ bnm, const float* __restrict__ bnv,
    float* __restrict__ pre)                 // [32][8][8][64]
{
  int wrp = threadIdx.x >> 6;
  int lane = threadIdx.x & 63;
  int n = RFL(blockIdx.x & 7);
  int t = RFL(blockIdx.x >> 3);
  int cog = RFL(wrp);
  int col = lane & 15, kg = lane >> 4;
  int co = cog * 16 + col;
  int yA = col >> 3, xA = col & 7;

  float inv = 1.0f / sqrtf(bnv[co] + 1e-5f);
  float g  = __fmul_rn(bng[co], inv);
  float bc = __fsub_rn(bnb[co], __fmul_rn(__fmul_rn(bnm[co], bng[co]), inv));

  const unsigned short* ibase = in + (size_t)(t * 8 + n) * 6400;

  ffrag acc[4];
  #pragma unroll
  for (int yy = 0; yy < 4; ++yy) {
    acc[yy][0] = 0.f; acc[yy][1] = 0.f; acc[yy][2] = 0.f; acc[yy][3] = 0.f;
  }
  #pragma unroll
  for (int tap = 0; tap < 9; ++tap) {
    const int ky = tap / 3, kx = tap % 3;
    #pragma unroll
    for (int kh = 0; kh < 2; ++kh) {
      bfrag av[4];
      #pragma unroll
      for (int yy = 0; yy < 4; ++yy) {
        const unsigned short* au =
            ibase + ((yy * 2 + yA + ky) * 10 + xA + kx) * 64 + kh * 32 + kg * 8;
        av[yy] = *(const bfrag*)au;
      }
      #pragma unroll
      for (int s = 0; s < 3; ++s) {
        const unsigned short* wu = wtl + (s * 9 + tap) * 4096 + cog * 1024 + kh * 32;
        bfrag bv = *(const bfrag*)(wu + col * 64 + kg * 8);
        #pragma unroll
        for (int yy = 0; yy < 4; ++yy)
          acc[yy] = __builtin_amdgcn_mfma_f32_16x16x32_bf16(av[yy], bv, acc[yy], 0, 0, 0);
      }
    }
  }
  #pragma unroll
  for (int yy = 0; yy < 4; ++yy)
    #pragma unroll
    for (int j = 0; j < 4; ++j) {
      int r16 = kg * 4 + j;
      int y = yy * 2 + (r16 >> 3), x = r16 & 7;
      pre[((size_t)((t * 8 + n) * 8 + y) * 8 + x) * 64 + co] =
          __fadd_rn(__fmul_rn(acc[yy][j], g), bc);
    }
}

// Fused lifpool8 + FC1 (512 blocks, same parallelism as old fc1). Each block
// recomputes pool+LIF for its n into LDS (bit-identical), then fc1 exactly.
__global__ __launch_bounds__(256) void k_fc1p(
    const float* __restrict__ pre,  // [32][8][8][64] (conv4M output)
    const float* __restrict__ w, float* __restrict__ out)  // out: s1 [32][256]
{
  __shared__ float sp[1024];        // [16pp][64co] for current t

  int tid = threadIdx.x;
  int lane = tid & 63;
  int n = RFL(blockIdx.x >> 6);
  int j = ((blockIdx.x & 63) * 4 + (tid >> 6)) & 255;

  float wr[16];
  #pragma unroll
  for (int u = 0; u < 16; ++u) wr[u] = w[j * 1024 + lane * 16 + u];

  float vp[4][4];
  #pragma unroll
  for (int k = 0; k < 4; ++k)
    #pragma unroll
    for (int q = 0; q < 4; ++q) vp[k][q] = 0.f;

  float v = 0.f;   // fc1 LIF state (uniform across lanes of the wave)

  #pragma unroll 1
  for (int t = 0; t < 4; ++t) {
    #pragma unroll
    for (int k = 0; k < 4; ++k) {
      int idx = k * 256 + tid;
      int pp = idx >> 6, co = idx & 63;
      int py = pp >> 2, px = pp & 3;
      const float* pb = pre + ((size_t)((t * 8 + n) * 8 + 2 * py) * 8 + 2 * px) * 64 + co;
      float spv = fmaxf(fmaxf(lif_upd(vp[k][0], pb[0]), lif_upd(vp[k][1], pb[64])),
                        fmaxf(lif_upd(vp[k][2], pb[8 * 64]), lif_upd(vp[k][3], pb[9 * 64])));
      sp[idx] = spv;
    }
    __syncthreads();

    float sum = 0.f;
    #pragma unroll
    for (int u = 0; u < 16; ++u) sum = fmaf(wr[u], sp[u * 64 + lane], sum);
    #pragma unroll
    for (int off = 32; off > 0; off >>= 1) sum += __shfl_xor(sum, off, 64);
    float s = lif_upd(v, sum);
    if (lane == 0) out[(t * 8 + n) * 256 + j] = s;
    __syncthreads();   // before overwriting sp next t
  }
}

// FC2: (8,256)@(110,256)^T + LIF.
__global__ __launch_bounds__(256) void k_fc2(
    const float* __restrict__ s1, const float* __restrict__ w, float* __restrict__ out)
{
  int wv = blockIdx.x * 4 + (threadIdx.x >> 6);
  int lane = threadIdx.x & 63;
  int j = wv % 110;
  int n = wv / 110;
  float wr[4];
  #pragma unroll
  for (int u = 0; u < 4; ++u) wr[u] = w[j * 256 + u * 64 + lane];
  float v = 0.f;
  #pragma unroll 1
  for (int t = 0; t < 4; ++t) {
    const float* sp = s1 + (t * 8 + n) * 256;
    float sum = 0.f;
    #pragma unroll
    for (int u = 0; u < 4; ++u) sum = fmaf(wr[u], sp[u * 64 + lane], sum);
    #pragma unroll
    for (int off = 32; off > 0; off >>= 1) sum += __shfl_xor(sum, off, 64);
    float s = lif_upd(v, sum);
    if (lane == 0) out[(t * 8 + n) * 110 + j] = s;
  }
}

// acc[n][g] = sum_t mean_{j<10} s2[t][n][g*10+j]
__global__ __launch_bounds__(128) void k_acc(const float* __restrict__ s2, float* __restrict__ out) {
  int id = threadIdx.x;
  if (id >= 88) return;
  int n = id / 11, g = id % 11;
  float a = 0.f;
  #pragma unroll 1
  for (int t = 0; t < 4; ++t) {
    float m = 0.f;
    #pragma unroll
    for (int jj = 0; jj < 10; ++jj) m = __fadd_rn(m, s2[(t * 8 + n) * 110 + g * 10 + jj]);
    a = __fadd_rn(a, __fdiv_rn(m, 10.0f));
  }
  out[n * 11 + g] = a;
}

extern "C" void kernel_launch(void* const* d_in, const int* in_sizes, int n_in,
                              void* d_out, int out_size, void* d_ws, size_t ws_size,
                              hipStream_t stream)
{
  const float* x  = (const float*)d_in[0];
  const float* w0 = (const float*)d_in[1];
  const float* wc = (const float*)d_in[2];
  const float* bg = (const float*)d_in[3];
  const float* bb = (const float*)d_in[4];
  const float* bm = (const float*)d_in[5];
  const float* bv = (const float*)d_in[6];
  const float* w1 = (const float*)d_in[7];
  const float* w2 = (const float*)d_in[8];
  float* out = (float*)d_out;

  // ---- workspace layout ----
  unsigned short* sp0 = (unsigned short*)d_ws;      // [32][66][66][64]  8,921,088
  unsigned short* sp1 = sp0 + 8921088;              // [32][34][34][64]  2,367,488
  unsigned short* sp2 = sp1 + 2367488;              // [32][18][18][64]    663,552
  unsigned short* sp3 = sp2 + 663552;               // [32][10][10][64]    204,800
  unsigned short* wt  = sp3 + 204800;               // [4][3][9][4096]     442,368
  float* fbase = (float*)((char*)d_ws + 25198592);
  float* sp4  = fbase;            // (unused)          32,768
  float* pre4 = sp4 + 32768;      // [32][8][8][64]   131,072
  float* s1   = pre4 + 131072;    // [32][256]          8,192
  float* s2   = s1 + 8192;        // [32][110]          3,520
  float* padx = (float*)((char*)d_ws + 25900800);   // [32][2][130][136] 1,131,520
  if (ws_size < (size_t)30426880) return;

  constexpr int WTL = 3 * 9 * 4096;   // per-layer wt stride (ushorts)

  k_prep<<<5492, 256, 0, stream>>>(wc, wt, sp0, x, padx);

  k_conv0<<<2048, 256, 0, stream>>>(padx, w0, bg, bb, bm, bv, sp0);

  k_convT<64><<<1024, 256, 0, stream>>>(sp0, wt + 0 * WTL, bg + 64,  bb + 64,  bm + 64,  bv + 64,  sp1);
  k_convT<32><<<256, 256, 0, stream>>>(sp1, wt + 1 * WTL, bg + 128, bb + 128, bm + 128, bv + 128, sp2);
  k_convT<16><<<64, 256, 0, stream>>>(sp2, wt + 2 * WTL, bg + 192, bb + 192, bm + 192, bv + 192, sp3);

  k_conv4M<<<32, 256, 0, stream>>>(sp3, wt + 3 * WTL, bg + 256, bb + 256, bm + 256, bv + 256, pre4);

  k_fc1p<<<512, 256, 0, stream>>>(pre4, w1, s1);
  k_fc2<<<220, 256, 0, stream>>>(s1, w2, s2);
  k_acc<<<1, 128, 0, stream>>>(s2, out);
}

// Round 25
// 116.909 us; speedup vs baseline: 1.0408x; 1.0408x over previous
//
#include <hip/hip_runtime.h>
#include <hip/hip_bf16.h>
#include <math.h>

#define RFL(x) __builtin_amdgcn_readfirstlane(x)

typedef short bfrag __attribute__((ext_vector_type(8)));   // 8 bf16 (4 VGPR)
typedef float ffrag __attribute__((ext_vector_type(4)));   // 4 f32 acc

// LIF: v = v + (x - v)/2 ; s = (v >= 1) ; v = s ? 0 : v   (exact rounding match)
static __device__ __forceinline__ float lif_upd(float& v, float x) {
  v = __fadd_rn(v, __fmul_rn(__fsub_rn(x, v), 0.5f));
  float s = (v >= 1.0f) ? 1.0f : 0.0f;
  v = (v >= 1.0f) ? 0.0f : v;
  return s;
}

static __device__ __forceinline__ unsigned short f2bf(float x) {
  __hip_bfloat16 h = __float2bfloat16(x);
  return *reinterpret_cast<unsigned short*>(&h);
}
static __device__ __forceinline__ float bf2f(unsigned short u) {
  __hip_bfloat16 h = *reinterpret_cast<__hip_bfloat16*>(&u);
  return __bfloat162float(h);
}

static __device__ __forceinline__ void zring(unsigned short* buf, int W2, int idx) {
  int PERIM = 4 * W2 - 4;
  int c8 = idx & 7;
  int r = idx >> 3;
  int p = r % PERIM; int pl = r / PERIM;
  int row, col;
  if (p < W2)            { row = 0;      col = p; }
  else if (p < 2 * W2)   { row = W2 - 1; col = p - W2; }
  else { int q = p - 2 * W2; row = 1 + (q >> 1); col = (q & 1) ? (W2 - 1) : 0; }
  *(uint4*)(buf + ((size_t)(pl * W2 + row) * W2 + col) * 64 + c8 * 8) =
      make_uint4(0u, 0u, 0u, 0u);
}

// One launch: weight 3-split (147,456) + halo zeroing (126,976) + x padding (1,131,520).
__global__ __launch_bounds__(256) void k_prep(
    const float* __restrict__ wc, unsigned short* __restrict__ wt,
    unsigned short* __restrict__ sp0, const float* __restrict__ x,
    float* __restrict__ padx)
{
  int id = blockIdx.x * 256 + threadIdx.x;
  if (id < 147456) {
    // weight split: wt[((l*3+s)*9+tap)*4096 + co*64 + ci]
    int tap = id % 9; int r = id / 9;
    int ci = r & 63; r >>= 6;
    int co = r & 63; int l = r >> 6;
    float w = wc[(size_t)(((l * 64 + co) * 64 + ci) * 9) + tap];
    unsigned short h0 = f2bf(w);  float r1 = __fsub_rn(w, bf2f(h0));
    unsigned short h1 = f2bf(r1); float r2 = __fsub_rn(r1, bf2f(h1));
    unsigned short h2 = f2bf(r2);
    size_t base = (size_t)((l * 3) * 9 + tap) * 4096 + co * 64 + ci;
    wt[base] = h0;
    wt[base + 9 * 4096] = h1;
    wt[base + 18 * 4096] = h2;
    return;
  }
  id -= 147456;
  if (id < 126976) {
    if (id < 66560)            zring(sp0,            66, id);
    else if (id < 100352)      zring(sp0 + 8921088,  34, id - 66560);
    else if (id < 117760)      zring(sp0 + 11288576, 18, id - 100352);
    else                       zring(sp0 + 11952128, 10, id - 117760);
    return;
  }
  id -= 126976;
  // pad x: padx[plane][130][136], interior (r=1..128, c=2..129) <- x[plane][r-1][c-2]
  if (id < 1131520) {
    int c = id % 136;
    int r = (id / 136) % 130;
    int plane = id / (136 * 130);
    float v = 0.f;
    if (r >= 1 && r <= 128 && c >= 2 && c <= 129)
      v = x[(size_t)plane * 16384 + (r - 1) * 128 + (c - 2)];
    padx[id] = v;
  }
}

// Layer 0 (known-good: WRITE == output, no spill): fused conv(2->64)+BN+LIF+2x2
// pool, padded input, co-blocked 4. Thread = 1 pooled px x 4 co.
__global__ __launch_bounds__(256, 4) void k_conv0(
    const float* __restrict__ px,  // [32][2][130][136] padded
    const float* __restrict__ w,   // [64][2][3][3]
    const float* __restrict__ bng, const float* __restrict__ bnb,
    const float* __restrict__ bnm, const float* __restrict__ bnv,
    unsigned short* __restrict__ out)
{
  int n   = RFL(blockIdx.x & 7);
  int b2  = blockIdx.x >> 3;          // [0,256)
  int cog = RFL(b2 & 15);             // 4-channel group
  int pp  = ((b2 >> 4) << 8) | threadIdx.x;   // [0,4096) pooled positions
  int py = pp >> 6, pxc = pp & 63;

  float gsc[4], bias[4];
  #pragma unroll
  for (int j = 0; j < 4; ++j) {
    int co = cog * 4 + j;
    float inv = 1.0f / sqrtf(bnv[co] + 1e-5f);
    gsc[j]  = __fmul_rn(bng[co], inv);
    bias[j] = __fsub_rn(bnb[co], __fmul_rn(__fmul_rn(bnm[co], bng[co]), inv));
  }

  float vm[4][4];
  #pragma unroll
  for (int j = 0; j < 4; ++j)
    #pragma unroll
    for (int q = 0; q < 4; ++q) vm[j][q] = 0.f;

  #pragma unroll 1
  for (int t = 0; t < 4; ++t) {
    float s[4][4];
    #pragma unroll
    for (int j = 0; j < 4; ++j)
      #pragma unroll
      for (int q = 0; q < 4; ++q) s[j][q] = 0.f;

    #pragma unroll
    for (int ci = 0; ci < 2; ++ci) {
      const float* pl = px + (size_t)((n * 4 + t) * 2 + ci) * 17680;
      float q[4][4];
      #pragma unroll
      for (int i = 0; i < 4; ++i) {
        const float* rp = pl + (2 * py + i) * 136 + 2 * pxc;
        float2 a = *(const float2*)(rp);
        float2 b = *(const float2*)(rp + 2);
        float2 c = *(const float2*)(rp + 4);
        q[i][0] = a.y; q[i][1] = b.x; q[i][2] = b.y; q[i][3] = c.x;
      }
      #pragma unroll
      for (int j = 0; j < 4; ++j) {
        const float* wp = w + (cog * 4 + j) * 18 + ci * 9;   // uniform -> s_load
        #pragma unroll
        for (int ky = 0; ky < 3; ++ky)
          #pragma unroll
          for (int kx = 0; kx < 3; ++kx) {
            float wv = wp[ky * 3 + kx];
            s[j][0] = fmaf(q[ky    ][kx    ], wv, s[j][0]);
            s[j][1] = fmaf(q[ky    ][kx + 1], wv, s[j][1]);
            s[j][2] = fmaf(q[ky + 1][kx    ], wv, s[j][2]);
            s[j][3] = fmaf(q[ky + 1][kx + 1], wv, s[j][3]);
          }
      }
    }
    ushort4 u4;
    unsigned short us[4];
    #pragma unroll
    for (int j = 0; j < 4; ++j) {
      float h0 = __fadd_rn(__fmul_rn(s[j][0], gsc[j]), bias[j]);
      float h1 = __fadd_rn(__fmul_rn(s[j][1], gsc[j]), bias[j]);
      float h2 = __fadd_rn(__fmul_rn(s[j][2], gsc[j]), bias[j]);
      float h3 = __fadd_rn(__fmul_rn(s[j][3], gsc[j]), bias[j]);
      float sp = fmaxf(fmaxf(lif_upd(vm[j][0], h0), lif_upd(vm[j][1], h1)),
                       fmaxf(lif_upd(vm[j][2], h2), lif_upd(vm[j][3], h3)));
      us[j] = (sp >= 0.5f) ? (unsigned short)0x3F80 : (unsigned short)0;
    }
    u4.x = us[0]; u4.y = us[1]; u4.z = us[2]; u4.w = us[3];
    size_t pix = (size_t)((t * 8 + n) * 66 + (py + 1)) * 66 + (pxc + 1);
    *(ushort4*)(out + pix * 64 + cog * 4) = u4;
  }
}

// MFMA conv(64->64)+BN+LIF+2x2 pool, LDS-staged & placement-agnostic.
// launch_bounds (256,3): REQUIRED — (256,4) forced VGPR 84->64 and spilled
// (R24: WRITE 20.5MB vs 4.7MB output, dur +20%). Staging via global_load_lds
// (linear LDS dest + inverse-swizzled SOURCE; read keeps the XOR). Per-wave
// (kx,kh) rotation decorrelates stall phases; setprio(1) favors MFMA bursts.
template<int H>
__global__ __launch_bounds__(256, 3) void k_convT(
    const unsigned short* __restrict__ in,   // [32][H+2][H+2][64] padded spikes
    const unsigned short* __restrict__ wtl,  // [3][9][64][64] bf16 (this layer)
    const float* __restrict__ bng, const float* __restrict__ bnb,
    const float* __restrict__ bnm, const float* __restrict__ bnv,
    unsigned short* __restrict__ osp)        // [32][H/2+2][H/2+2][64] padded
{
  constexpr int W2 = H + 2;
  constexpr int HP2 = H / 2 + 2;
  constexpr int XT = H / 16;
  constexpr int YT = H / 2;                  // YS = 2
  constexpr int XS = 18;
  constexpr int TILE = 4 * 4 * XS * 64;      // 18432 ushorts (36 KB)
  constexpr int CHUNKS = TILE / 8;           // 2304 16B chunks

  __shared__ unsigned short tile[TILE];

  int tid = threadIdx.x;
  int lane = tid & 63;
  int cog = tid >> 6;                        // wave = cog
  int bid = blockIdx.x;
  int n  = RFL(bid & 7);
  int rest = bid >> 3;
  int xt = RFL(rest % XT);
  int yt = RFL(rest / XT);
  int x0 = xt * 16, y0 = yt * 2;
  int col = lane & 15, kg = lane >> 4;
  int co = cog * 16 + col;

  float inv = 1.0f / sqrtf(bnv[co] + 1e-5f);
  float g  = __fmul_rn(bng[co], inv);
  float bc = __fsub_rn(bnb[co], __fmul_rn(__fmul_rn(bnm[co], bng[co]), inv));

  // ---- stage all 4 timesteps: global_load_lds, LDS linear, source pre-swizzled ----
  #pragma unroll
  for (int it = 0; it < CHUNKS / 256; ++it) {
    int c = it * 256 + tid;
    int slot = c & 7;                // 16B slot within pix line
    int pix = c >> 3;                // (tt*4+row)*18 + pxl
    int pxl = pix % XS;
    int rw  = pix / XS;              // [0,16)
    int row = rw & 3, tt = rw >> 2;
    int src16 = slot ^ (pxl & 7);    // inverse swizzle (XOR involution)
    const unsigned short* s = in +
        ((size_t)(tt * 8 + n) * W2 * W2 + (size_t)(y0 + row) * W2 + (x0 + pxl)) * 64 + src16 * 8;
    __builtin_amdgcn_global_load_lds(
        (const __attribute__((address_space(1))) unsigned int*)s,
        (__attribute__((address_space(3))) unsigned int*)&tile[(it * 256 + cog * 64) * 8],
        16, 0, 0);
  }
  __syncthreads();

  // ---- MFMA: rotated (kx,kh) per wave, bv[3][3] preloaded, tp inner ----
  ffrag acc[4][2];
  #pragma unroll
  for (int tt = 0; tt < 4; ++tt)
    #pragma unroll
    for (int yy = 0; yy < 2; ++yy) {
      acc[tt][yy][0] = 0.f; acc[tt][yy][1] = 0.f;
      acc[tt][yy][2] = 0.f; acc[tt][yy][3] = 0.f;
    }

  #pragma unroll
  for (int kxi = 0; kxi < 3; ++kxi) {
    int kxr = kxi + cog;                     // wave-uniform rotation
    const int kx = (kxr >= 3) ? ((kxr >= 6) ? kxr - 6 : kxr - 3) : kxr;
    const int pxl = kx + col;
    const int swz = (pxl & 7) << 3;
    #pragma unroll
    for (int khi = 0; khi < 2; ++khi) {
      const int kh = khi ^ ((cog >> 1) & 1); // second-level phase split
      bfrag bv[3][3];                        // [ky][s] — 9 batched global loads
      #pragma unroll
      for (int ky = 0; ky < 3; ++ky)
        #pragma unroll
        for (int s = 0; s < 3; ++s)
          bv[ky][s] = *(const bfrag*)(wtl + (size_t)(s * 9 + ky * 3 + kx) * 4096 +
                                      cog * 1024 + col * 64 + kh * 32 + kg * 8);
      #pragma unroll
      for (int tp = 0; tp < 2; ++tp) {       // tt-pair: {0,1}, {2,3}
        bfrag ar[2][4];                      // [tt within pair][row 0..3]
        #pragma unroll
        for (int ti = 0; ti < 2; ++ti)
          #pragma unroll
          for (int rr = 0; rr < 4; ++rr)
            ar[ti][rr] = *(const bfrag*)&tile[(((tp * 2 + ti) * 4 + rr) * XS + pxl) * 64 +
                                              ((kh * 32 + kg * 8) ^ swz)];
        __builtin_amdgcn_s_setprio(1);
        #pragma unroll
        for (int ky = 0; ky < 3; ++ky)
          #pragma unroll
          for (int s = 0; s < 3; ++s)
            #pragma unroll
            for (int ti = 0; ti < 2; ++ti)
              #pragma unroll
              for (int yy = 0; yy < 2; ++yy)
                acc[tp * 2 + ti][yy] = __builtin_amdgcn_mfma_f32_16x16x32_bf16(
                    ar[ti][yy + ky], bv[ky][s], acc[tp * 2 + ti][yy], 0, 0, 0);
        __builtin_amdgcn_s_setprio(0);
      }
    }
  }

  // ---- BN + LIF (t-sequential) + 2x2 pool -> pack (aliased into tile) ----
  float v[2][4];
  #pragma unroll
  for (int yy = 0; yy < 2; ++yy)
    #pragma unroll
    for (int j = 0; j < 4; ++j) v[yy][j] = 0.f;

  unsigned short sp[4][2];
  #pragma unroll
  for (int tt = 0; tt < 4; ++tt) {
    float s0[4], s1[4];
    #pragma unroll
    for (int j = 0; j < 4; ++j) {
      s0[j] = lif_upd(v[0][j], __fadd_rn(__fmul_rn(acc[tt][0][j], g), bc));
      s1[j] = lif_upd(v[1][j], __fadd_rn(__fmul_rn(acc[tt][1][j], g), bc));
    }
    #pragma unroll
    for (int b2 = 0; b2 < 2; ++b2) {
      float m = fmaxf(fmaxf(s0[2 * b2], s0[2 * b2 + 1]),
                      fmaxf(s1[2 * b2], s1[2 * b2 + 1]));
      sp[tt][b2] = (m >= 0.5f) ? (unsigned short)0x3F80 : (unsigned short)0;
    }
  }
  __syncthreads();   // all waves done reading tile
  #pragma unroll
  for (int tt = 0; tt < 4; ++tt)
    #pragma unroll
    for (int b2 = 0; b2 < 2; ++b2)
      tile[(tt * 8 + kg * 2 + b2) * 64 + co] = sp[tt][b2];
  __syncthreads();

  // ---- full-line write: 256 threads = 4t x 8ppx x 8 chunks ----
  {
    int c16 = tid & 7, ppx = (tid >> 3) & 7, tt = tid >> 6;
    uint4 d = *(const uint4*)&tile[(tt * 8 + ppx) * 64 + c16 * 8];
    *(uint4*)(osp + ((size_t)((tt * 8 + n) * HP2 + (yt + 1)) * HP2 +
                     (xt * 8 + ppx + 1)) * 64 + c16 * 8) = d;
  }
}

// Layer 4 (H=8): MFMA conv + BN, t-parallel (no LIF). A row=(y_off,x). n = blockIdx&7.
__global__ __launch_bounds__(256, 2) void k_conv4M(
    const unsigned short* __restrict__ in,   // [32][10][10][64] bf16
    const unsigned short* __restrict__ wtl,  // [3][9][64][64] bf16 (layer 4)
    const float* __restrict__ bng, const float* __restrict__ bnb,
    const float* __restrict__ bnm, const float* __restrict__ bnv,
    float* __restrict__ pre)                 // [32][8][8][64]
{
  int wrp = threadIdx.x >> 6;
  int lane = threadIdx.x & 63;
  int n = RFL(blockIdx.x & 7);
  int t = RFL(blockIdx.x >> 3);
  int cog = RFL(wrp);
  int col = lane & 15, kg = lane >> 4;
  int co = cog * 16 + col;
  int yA = col >> 3, xA = col & 7;

  float inv = 1.0f / sqrtf(bnv[co] + 1e-5f);
  float g  = __fmul_rn(bng[co], inv);
  float bc = __fsub_rn(bnb[co], __fmul_rn(__fmul_rn(bnm[co], bng[co]), inv));

  const unsigned short* ibase = in + (size_t)(t * 8 + n) * 6400;

  ffrag acc[4];
  #pragma unroll
  for (int yy = 0; yy < 4; ++yy) {
    acc[yy][0] = 0.f; acc[yy][1] = 0.f; acc[yy][2] = 0.f; acc[yy][3] = 0.f;
  }
  #pragma unroll
  for (int tap = 0; tap < 9; ++tap) {
    const int ky = tap / 3, kx = tap % 3;
    #pragma unroll
    for (int kh = 0; kh < 2; ++kh) {
      bfrag av[4];
      #pragma unroll
      for (int yy = 0; yy < 4; ++yy) {
        const unsigned short* au =
            ibase + ((yy * 2 + yA + ky) * 10 + xA + kx) * 64 + kh * 32 + kg * 8;
        av[yy] = *(const bfrag*)au;
      }
      #pragma unroll
      for (int s = 0; s < 3; ++s) {
        const unsigned short* wu = wtl + (s * 9 + tap) * 4096 + cog * 1024 + kh * 32;
        bfrag bv = *(const bfrag*)(wu + col * 64 + kg * 8);
        #pragma unroll
        for (int yy = 0; yy < 4; ++yy)
          acc[yy] = __builtin_amdgcn_mfma_f32_16x16x32_bf16(av[yy], bv, acc[yy], 0, 0, 0);
      }
    }
  }
  #pragma unroll
  for (int yy = 0; yy < 4; ++yy)
    #pragma unroll
    for (int j = 0; j < 4; ++j) {
      int r16 = kg * 4 + j;
      int y = yy * 2 + (r16 >> 3), x = r16 & 7;
      pre[((size_t)((t * 8 + n) * 8 + y) * 8 + x) * 64 + co] =
          __fadd_rn(__fmul_rn(acc[yy][j], g), bc);
    }
}

// Fused lifpool8 + FC1 (512 blocks, same parallelism as old fc1). Each block
// recomputes pool+LIF for its n into LDS (bit-identical), then fc1 exactly.
__global__ __launch_bounds__(256) void k_fc1p(
    const float* __restrict__ pre,  // [32][8][8][64] (conv4M output)
    const float* __restrict__ w, float* __restrict__ out)  // out: s1 [32][256]
{
  __shared__ float sp[1024];        // [16pp][64co] for current t

  int tid = threadIdx.x;
  int lane = tid & 63;
  int n = RFL(blockIdx.x >> 6);
  int j = ((blockIdx.x & 63) * 4 + (tid >> 6)) & 255;

  float wr[16];
  #pragma unroll
  for (int u = 0; u < 16; ++u) wr[u] = w[j * 1024 + lane * 16 + u];

  float vp[4][4];
  #pragma unroll
  for (int k = 0; k < 4; ++k)
    #pragma unroll
    for (int q = 0; q < 4; ++q) vp[k][q] = 0.f;

  float v = 0.f;   // fc1 LIF state (uniform across lanes of the wave)

  #pragma unroll 1
  for (int t = 0; t < 4; ++t) {
    #pragma unroll
    for (int k = 0; k < 4; ++k) {
      int idx = k * 256 + tid;
      int pp = idx >> 6, co = idx & 63;
      int py = pp >> 2, px = pp & 3;
      const float* pb = pre + ((size_t)((t * 8 + n) * 8 + 2 * py) * 8 + 2 * px) * 64 + co;
      float spv = fmaxf(fmaxf(lif_upd(vp[k][0], pb[0]), lif_upd(vp[k][1], pb[64])),
                        fmaxf(lif_upd(vp[k][2], pb[8 * 64]), lif_upd(vp[k][3], pb[9 * 64])));
      sp[idx] = spv;
    }
    __syncthreads();

    float sum = 0.f;
    #pragma unroll
    for (int u = 0; u < 16; ++u) sum = fmaf(wr[u], sp[u * 64 + lane], sum);
    #pragma unroll
    for (int off = 32; off > 0; off >>= 1) sum += __shfl_xor(sum, off, 64);
    float s = lif_upd(v, sum);
    if (lane == 0) out[(t * 8 + n) * 256 + j] = s;
    __syncthreads();   // before overwriting sp next t
  }
}

// FC2: (8,256)@(110,256)^T + LIF.
__global__ __launch_bounds__(256) void k_fc2(
    const float* __restrict__ s1, const float* __restrict__ w, float* __restrict__ out)
{
  int wv = blockIdx.x * 4 + (threadIdx.x >> 6);
  int lane = threadIdx.x & 63;
  int j = wv % 110;
  int n = wv / 110;
  float wr[4];
  #pragma unroll
  for (int u = 0; u < 4; ++u) wr[u] = w[j * 256 + u * 64 + lane];
  float v = 0.f;
  #pragma unroll 1
  for (int t = 0; t < 4; ++t) {
    const float* sp = s1 + (t * 8 + n) * 256;
    float sum = 0.f;
    #pragma unroll
    for (int u = 0; u < 4; ++u) sum = fmaf(wr[u], sp[u * 64 + lane], sum);
    #pragma unroll
    for (int off = 32; off > 0; off >>= 1) sum += __shfl_xor(sum, off, 64);
    float s = lif_upd(v, sum);
    if (lane == 0) out[(t * 8 + n) * 110 + j] = s;
  }
}

// acc[n][g] = sum_t mean_{j<10} s2[t][n][g*10+j]
__global__ __launch_bounds__(128) void k_acc(const float* __restrict__ s2, float* __restrict__ out) {
  int id = threadIdx.x;
  if (id >= 88) return;
  int n = id / 11, g = id % 11;
  float a = 0.f;
  #pragma unroll 1
  for (int t = 0; t < 4; ++t) {
    float m = 0.f;
    #pragma unroll
    for (int jj = 0; jj < 10; ++jj) m = __fadd_rn(m, s2[(t * 8 + n) * 110 + g * 10 + jj]);
    a = __fadd_rn(a, __fdiv_rn(m, 10.0f));
  }
  out[n * 11 + g] = a;
}

extern "C" void kernel_launch(void* const* d_in, const int* in_sizes, int n_in,
                              void* d_out, int out_size, void* d_ws, size_t ws_size,
                              hipStream_t stream)
{
  const float* x  = (const float*)d_in[0];
  const float* w0 = (const float*)d_in[1];
  const float* wc = (const float*)d_in[2];
  const float* bg = (const float*)d_in[3];
  const float* bb = (const float*)d_in[4];
  const float* bm = (const float*)d_in[5];
  const float* bv = (const float*)d_in[6];
  const float* w1 = (const float*)d_in[7];
  const float* w2 = (const float*)d_in[8];
  float* out = (float*)d_out;

  // ---- workspace layout ----
  unsigned short* sp0 = (unsigned short*)d_ws;      // [32][66][66][64]  8,921,088
  unsigned short* sp1 = sp0 + 8921088;              // [32][34][34][64]  2,367,488
  unsigned short* sp2 = sp1 + 2367488;              // [32][18][18][64]    663,552
  unsigned short* sp3 = sp2 + 663552;               // [32][10][10][64]    204,800
  unsigned short* wt  = sp3 + 204800;               // [4][3][9][4096]     442,368
  float* fbase = (float*)((char*)d_ws + 25198592);
  float* sp4  = fbase;            // (unused)          32,768
  float* pre4 = sp4 + 32768;      // [32][8][8][64]   131,072
  float* s1   = pre4 + 131072;    // [32][256]          8,192
  float* s2   = s1 + 8192;        // [32][110]          3,520
  float* padx = (float*)((char*)d_ws + 25900800);   // [32][2][130][136] 1,131,520
  if (ws_size < (size_t)30426880) return;

  constexpr int WTL = 3 * 9 * 4096;   // per-layer wt stride (ushorts)

  k_prep<<<5492, 256, 0, stream>>>(wc, wt, sp0, x, padx);

  k_conv0<<<2048, 256, 0, stream>>>(padx, w0, bg, bb, bm, bv, sp0);

  k_convT<64><<<1024, 256, 0, stream>>>(sp0, wt + 0 * WTL, bg + 64,  bb + 64,  bm + 64,  bv + 64,  sp1);
  k_convT<32><<<256, 256, 0, stream>>>(sp1, wt + 1 * WTL, bg + 128, bb + 128, bm + 128, bv + 128, sp2);
  k_convT<16><<<64, 256, 0, stream>>>(sp2, wt + 2 * WTL, bg + 192, bb + 192, bm + 192, bv + 192, sp3);

  k_conv4M<<<32, 256, 0, stream>>>(sp3, wt + 3 * WTL, bg + 256, bb + 256, bm + 256, bv + 256, pre4);

  k_fc1p<<<512, 256, 0, stream>>>(pre4, w1, s1);
  k_fc2<<<220, 256, 0, stream>>>(s1, w2, s2);
  k_acc<<<1, 128, 0, stream>>>(s2, out);
}

// Round 26
// 116.422 us; speedup vs baseline: 1.0451x; 1.0042x over previous
//
#include <hip/hip_runtime.h>
#include <hip/hip_bf16.h>
#include <math.h>

#define RFL(x) __builtin_amdgcn_readfirstlane(x)

typedef short bfrag __attribute__((ext_vector_type(8)));   // 8 bf16 (4 VGPR)
typedef float ffrag __attribute__((ext_vector_type(4)));   // 4 f32 acc

// LIF: v = v + (x - v)/2 ; s = (v >= 1) ; v = s ? 0 : v   (exact rounding match)
static __device__ __forceinline__ float lif_upd(float& v, float x) {
  v = __fadd_rn(v, __fmul_rn(__fsub_rn(x, v), 0.5f));
  float s = (v >= 1.0f) ? 1.0f : 0.0f;
  v = (v >= 1.0f) ? 0.0f : v;
  return s;
}

static __device__ __forceinline__ unsigned short f2bf(float x) {
  __hip_bfloat16 h = __float2bfloat16(x);
  return *reinterpret_cast<unsigned short*>(&h);
}
static __device__ __forceinline__ float bf2f(unsigned short u) {
  __hip_bfloat16 h = *reinterpret_cast<__hip_bfloat16*>(&u);
  return __bfloat162float(h);
}

static __device__ __forceinline__ void zring(unsigned short* buf, int W2, int idx) {
  int PERIM = 4 * W2 - 4;
  int c8 = idx & 7;
  int r = idx >> 3;
  int p = r % PERIM; int pl = r / PERIM;
  int row, col;
  if (p < W2)            { row = 0;      col = p; }
  else if (p < 2 * W2)   { row = W2 - 1; col = p - W2; }
  else { int q = p - 2 * W2; row = 1 + (q >> 1); col = (q & 1) ? (W2 - 1) : 0; }
  *(uint4*)(buf + ((size_t)(pl * W2 + row) * W2 + col) * 64 + c8 * 8) =
      make_uint4(0u, 0u, 0u, 0u);
}

// One launch: weight 3-split (147,456) + halo zeroing (126,976) + x padding (1,131,520).
__global__ __launch_bounds__(256) void k_prep(
    const float* __restrict__ wc, unsigned short* __restrict__ wt,
    unsigned short* __restrict__ sp0, const float* __restrict__ x,
    float* __restrict__ padx)
{
  int id = blockIdx.x * 256 + threadIdx.x;
  if (id < 147456) {
    // weight split: wt[((l*3+s)*9+tap)*4096 + co*64 + ci]
    int tap = id % 9; int r = id / 9;
    int ci = r & 63; r >>= 6;
    int co = r & 63; int l = r >> 6;
    float w = wc[(size_t)(((l * 64 + co) * 64 + ci) * 9) + tap];
    unsigned short h0 = f2bf(w);  float r1 = __fsub_rn(w, bf2f(h0));
    unsigned short h1 = f2bf(r1); float r2 = __fsub_rn(r1, bf2f(h1));
    unsigned short h2 = f2bf(r2);
    size_t base = (size_t)((l * 3) * 9 + tap) * 4096 + co * 64 + ci;
    wt[base] = h0;
    wt[base + 9 * 4096] = h1;
    wt[base + 18 * 4096] = h2;
    return;
  }
  id -= 147456;
  if (id < 126976) {
    if (id < 66560)            zring(sp0,            66, id);
    else if (id < 100352)      zring(sp0 + 8921088,  34, id - 66560);
    else if (id < 117760)      zring(sp0 + 11288576, 18, id - 100352);
    else                       zring(sp0 + 11952128, 10, id - 117760);
    return;
  }
  id -= 126976;
  // pad x: padx[plane][130][136], interior (r=1..128, c=2..129) <- x[plane][r-1][c-2]
  if (id < 1131520) {
    int c = id % 136;
    int r = (id / 136) % 130;
    int plane = id / (136 * 130);
    float v = 0.f;
    if (r >= 1 && r <= 128 && c >= 2 && c <= 129)
      v = x[(size_t)plane * 16384 + (r - 1) * 128 + (c - 2)];
    padx[id] = v;
  }
}

// Layer 0 (known-good: WRITE == output, no spill): fused conv(2->64)+BN+LIF+2x2
// pool, padded input, co-blocked 4. Thread = 1 pooled px x 4 co.
__global__ __launch_bounds__(256, 4) void k_conv0(
    const float* __restrict__ px,  // [32][2][130][136] padded
    const float* __restrict__ w,   // [64][2][3][3]
    const float* __restrict__ bng, const float* __restrict__ bnb,
    const float* __restrict__ bnm, const float* __restrict__ bnv,
    unsigned short* __restrict__ out)
{
  int n   = RFL(blockIdx.x & 7);
  int b2  = blockIdx.x >> 3;          // [0,256)
  int cog = RFL(b2 & 15);             // 4-channel group
  int pp  = ((b2 >> 4) << 8) | threadIdx.x;   // [0,4096) pooled positions
  int py = pp >> 6, pxc = pp & 63;

  float gsc[4], bias[4];
  #pragma unroll
  for (int j = 0; j < 4; ++j) {
    int co = cog * 4 + j;
    float inv = 1.0f / sqrtf(bnv[co] + 1e-5f);
    gsc[j]  = __fmul_rn(bng[co], inv);
    bias[j] = __fsub_rn(bnb[co], __fmul_rn(__fmul_rn(bnm[co], bng[co]), inv));
  }

  float vm[4][4];
  #pragma unroll
  for (int j = 0; j < 4; ++j)
    #pragma unroll
    for (int q = 0; q < 4; ++q) vm[j][q] = 0.f;

  #pragma unroll 1
  for (int t = 0; t < 4; ++t) {
    float s[4][4];
    #pragma unroll
    for (int j = 0; j < 4; ++j)
      #pragma unroll
      for (int q = 0; q < 4; ++q) s[j][q] = 0.f;

    #pragma unroll
    for (int ci = 0; ci < 2; ++ci) {
      const float* pl = px + (size_t)((n * 4 + t) * 2 + ci) * 17680;
      float q[4][4];
      #pragma unroll
      for (int i = 0; i < 4; ++i) {
        const float* rp = pl + (2 * py + i) * 136 + 2 * pxc;
        float2 a = *(const float2*)(rp);
        float2 b = *(const float2*)(rp + 2);
        float2 c = *(const float2*)(rp + 4);
        q[i][0] = a.y; q[i][1] = b.x; q[i][2] = b.y; q[i][3] = c.x;
      }
      #pragma unroll
      for (int j = 0; j < 4; ++j) {
        const float* wp = w + (cog * 4 + j) * 18 + ci * 9;   // uniform -> s_load
        #pragma unroll
        for (int ky = 0; ky < 3; ++ky)
          #pragma unroll
          for (int kx = 0; kx < 3; ++kx) {
            float wv = wp[ky * 3 + kx];
            s[j][0] = fmaf(q[ky    ][kx    ], wv, s[j][0]);
            s[j][1] = fmaf(q[ky    ][kx + 1], wv, s[j][1]);
            s[j][2] = fmaf(q[ky + 1][kx    ], wv, s[j][2]);
            s[j][3] = fmaf(q[ky + 1][kx + 1], wv, s[j][3]);
          }
      }
    }
    ushort4 u4;
    unsigned short us[4];
    #pragma unroll
    for (int j = 0; j < 4; ++j) {
      float h0 = __fadd_rn(__fmul_rn(s[j][0], gsc[j]), bias[j]);
      float h1 = __fadd_rn(__fmul_rn(s[j][1], gsc[j]), bias[j]);
      float h2 = __fadd_rn(__fmul_rn(s[j][2], gsc[j]), bias[j]);
      float h3 = __fadd_rn(__fmul_rn(s[j][3], gsc[j]), bias[j]);
      float sp = fmaxf(fmaxf(lif_upd(vm[j][0], h0), lif_upd(vm[j][1], h1)),
                       fmaxf(lif_upd(vm[j][2], h2), lif_upd(vm[j][3], h3)));
      us[j] = (sp >= 0.5f) ? (unsigned short)0x3F80 : (unsigned short)0;
    }
    u4.x = us[0]; u4.y = us[1]; u4.z = us[2]; u4.w = us[3];
    size_t pix = (size_t)((t * 8 + n) * 66 + (py + 1)) * 66 + (pxc + 1);
    *(ushort4*)(out + pix * 64 + cog * 4) = u4;
  }
}

// MFMA conv(64->64)+BN+LIF+2x2 pool, LDS-staged & placement-agnostic.
// launch_bounds (256,3): REQUIRED — (256,4) forced VGPR 84->64 and spilled
// (R24: WRITE 20.5MB vs 4.7MB output, dur +20%). Staging via global_load_lds
// (linear LDS dest + inverse-swizzled SOURCE; read keeps the XOR). Per-wave
// (kx,kh) rotation decorrelates stall phases; setprio(1) favors MFMA bursts.
template<int H>
__global__ __launch_bounds__(256, 3) void k_convT(
    const unsigned short* __restrict__ in,   // [32][H+2][H+2][64] padded spikes
    const unsigned short* __restrict__ wtl,  // [3][9][64][64] bf16 (this layer)
    const float* __restrict__ bng, const float* __restrict__ bnb,
    const float* __restrict__ bnm, const float* __restrict__ bnv,
    unsigned short* __restrict__ osp)        // [32][H/2+2][H/2+2][64] padded
{
  constexpr int W2 = H + 2;
  constexpr int HP2 = H / 2 + 2;
  constexpr int XT = H / 16;
  constexpr int YT = H / 2;                  // YS = 2
  constexpr int XS = 18;
  constexpr int TILE = 4 * 4 * XS * 64;      // 18432 ushorts (36 KB)
  constexpr int CHUNKS = TILE / 8;           // 2304 16B chunks

  __shared__ unsigned short tile[TILE];

  int tid = threadIdx.x;
  int lane = tid & 63;
  int cog = tid >> 6;                        // wave = cog
  int bid = blockIdx.x;
  int n  = RFL(bid & 7);
  int rest = bid >> 3;
  int xt = RFL(rest % XT);
  int yt = RFL(rest / XT);
  int x0 = xt * 16, y0 = yt * 2;
  int col = lane & 15, kg = lane >> 4;
  int co = cog * 16 + col;

  float inv = 1.0f / sqrtf(bnv[co] + 1e-5f);
  float g  = __fmul_rn(bng[co], inv);
  float bc = __fsub_rn(bnb[co], __fmul_rn(__fmul_rn(bnm[co], bng[co]), inv));

  // ---- stage all 4 timesteps: global_load_lds, LDS linear, source pre-swizzled ----
  #pragma unroll
  for (int it = 0; it < CHUNKS / 256; ++it) {
    int c = it * 256 + tid;
    int slot = c & 7;                // 16B slot within pix line
    int pix = c >> 3;                // (tt*4+row)*18 + pxl
    int pxl = pix % XS;
    int rw  = pix / XS;              // [0,16)
    int row = rw & 3, tt = rw >> 2;
    int src16 = slot ^ (pxl & 7);    // inverse swizzle (XOR involution)
    const unsigned short* s = in +
        ((size_t)(tt * 8 + n) * W2 * W2 + (size_t)(y0 + row) * W2 + (x0 + pxl)) * 64 + src16 * 8;
    __builtin_amdgcn_global_load_lds(
        (const __attribute__((address_space(1))) unsigned int*)s,
        (__attribute__((address_space(3))) unsigned int*)&tile[(it * 256 + cog * 64) * 8],
        16, 0, 0);
  }
  __syncthreads();

  // ---- MFMA: rotated (kx,kh) per wave, bv[3][3] preloaded, tp inner ----
  ffrag acc[4][2];
  #pragma unroll
  for (int tt = 0; tt < 4; ++tt)
    #pragma unroll
    for (int yy = 0; yy < 2; ++yy) {
      acc[tt][yy][0] = 0.f; acc[tt][yy][1] = 0.f;
      acc[tt][yy][2] = 0.f; acc[tt][yy][3] = 0.f;
    }

  #pragma unroll
  for (int kxi = 0; kxi < 3; ++kxi) {
    int kxr = kxi + cog;                     // wave-uniform rotation
    const int kx = (kxr >= 3) ? ((kxr >= 6) ? kxr - 6 : kxr - 3) : kxr;
    const int pxl = kx + col;
    const int swz = (pxl & 7) << 3;
    #pragma unroll
    for (int khi = 0; khi < 2; ++khi) {
      const int kh = khi ^ ((cog >> 1) & 1); // second-level phase split
      bfrag bv[3][3];                        // [ky][s] — 9 batched global loads
      #pragma unroll
      for (int ky = 0; ky < 3; ++ky)
        #pragma unroll
        for (int s = 0; s < 3; ++s)
          bv[ky][s] = *(const bfrag*)(wtl + (size_t)(s * 9 + ky * 3 + kx) * 4096 +
                                      cog * 1024 + col * 64 + kh * 32 + kg * 8);
      #pragma unroll
      for (int tp = 0; tp < 2; ++tp) {       // tt-pair: {0,1}, {2,3}
        bfrag ar[2][4];                      // [tt within pair][row 0..3]
        #pragma unroll
        for (int ti = 0; ti < 2; ++ti)
          #pragma unroll
          for (int rr = 0; rr < 4; ++rr)
            ar[ti][rr] = *(const bfrag*)&tile[(((tp * 2 + ti) * 4 + rr) * XS + pxl) * 64 +
                                              ((kh * 32 + kg * 8) ^ swz)];
        __builtin_amdgcn_s_setprio(1);
        #pragma unroll
        for (int ky = 0; ky < 3; ++ky)
          #pragma unroll
          for (int s = 0; s < 3; ++s)
            #pragma unroll
            for (int ti = 0; ti < 2; ++ti)
              #pragma unroll
              for (int yy = 0; yy < 2; ++yy)
                acc[tp * 2 + ti][yy] = __builtin_amdgcn_mfma_f32_16x16x32_bf16(
                    ar[ti][yy + ky], bv[ky][s], acc[tp * 2 + ti][yy], 0, 0, 0);
        __builtin_amdgcn_s_setprio(0);
      }
    }
  }

  // ---- BN + LIF (t-sequential) + 2x2 pool -> pack (aliased into tile) ----
  float v[2][4];
  #pragma unroll
  for (int yy = 0; yy < 2; ++yy)
    #pragma unroll
    for (int j = 0; j < 4; ++j) v[yy][j] = 0.f;

  unsigned short sp[4][2];
  #pragma unroll
  for (int tt = 0; tt < 4; ++tt) {
    float s0[4], s1[4];
    #pragma unroll
    for (int j = 0; j < 4; ++j) {
      s0[j] = lif_upd(v[0][j], __fadd_rn(__fmul_rn(acc[tt][0][j], g), bc));
      s1[j] = lif_upd(v[1][j], __fadd_rn(__fmul_rn(acc[tt][1][j], g), bc));
    }
    #pragma unroll
    for (int b2 = 0; b2 < 2; ++b2) {
      float m = fmaxf(fmaxf(s0[2 * b2], s0[2 * b2 + 1]),
                      fmaxf(s1[2 * b2], s1[2 * b2 + 1]));
      sp[tt][b2] = (m >= 0.5f) ? (unsigned short)0x3F80 : (unsigned short)0;
    }
  }
  __syncthreads();   // all waves done reading tile
  #pragma unroll
  for (int tt = 0; tt < 4; ++tt)
    #pragma unroll
    for (int b2 = 0; b2 < 2; ++b2)
      tile[(tt * 8 + kg * 2 + b2) * 64 + co] = sp[tt][b2];
  __syncthreads();

  // ---- full-line write: 256 threads = 4t x 8ppx x 8 chunks ----
  {
    int c16 = tid & 7, ppx = (tid >> 3) & 7, tt = tid >> 6;
    uint4 d = *(const uint4*)&tile[(tt * 8 + ppx) * 64 + c16 * 8];
    *(uint4*)(osp + ((size_t)((tt * 8 + n) * HP2 + (yt + 1)) * HP2 +
                     (xt * 8 + ppx + 1)) * 64 + c16 * 8) = d;
  }
}

// Layer 4 (H=8): MFMA conv + BN, t-parallel (no LIF). A row=(y_off,x). n = blockIdx&7.
__global__ __launch_bounds__(256, 2) void k_conv4M(
    const unsigned short* __restrict__ in,   // [32][10][10][64] bf16
    const unsigned short* __restrict__ wtl,  // [3][9][64][64] bf16 (layer 4)
    const float* __restrict__ bng, const float* __restrict__ bnb,
    const float* __restrict__ bnm, const float* __restrict__ bnv,
    float* __restrict__ pre)                 // [32][8][8][64]
{
  int wrp = threadIdx.x >> 6;
  int lane = threadIdx.x & 63;
  int n = RFL(blockIdx.x & 7);
  int t = RFL(blockIdx.x >> 3);
  int cog = RFL(wrp);
  int col = lane & 15, kg = lane >> 4;
  int co = cog * 16 + col;
  int yA = col >> 3, xA = col & 7;

  float inv = 1.0f / sqrtf(bnv[co] + 1e-5f);
  float g  = __fmul_rn(bng[co], inv);
  float bc = __fsub_rn(bnb[co], __fmul_rn(__fmul_rn(bnm[co], bng[co]), inv));

  const unsigned short* ibase = in + (size_t)(t * 8 + n) * 6400;

  ffrag acc[4];
  #pragma unroll
  for (int yy = 0; yy < 4; ++yy) {
    acc[yy][0] = 0.f; acc[yy][1] = 0.f; acc[yy][2] = 0.f; acc[yy][3] = 0.f;
  }
  #pragma unroll
  for (int tap = 0; tap < 9; ++tap) {
    const int ky = tap / 3, kx = tap % 3;
    #pragma unroll
    for (int kh = 0; kh < 2; ++kh) {
      bfrag av[4];
      #pragma unroll
      for (int yy = 0; yy < 4; ++yy) {
        const unsigned short* au =
            ibase + ((yy * 2 + yA + ky) * 10 + xA + kx) * 64 + kh * 32 + kg * 8;
        av[yy] = *(const bfrag*)au;
      }
      #pragma unroll
      for (int s = 0; s < 3; ++s) {
        const unsigned short* wu = wtl + (s * 9 + tap) * 4096 + cog * 1024 + kh * 32;
        bfrag bv = *(const bfrag*)(wu + col * 64 + kg * 8);
        #pragma unroll
        for (int yy = 0; yy < 4; ++yy)
          acc[yy] = __builtin_amdgcn_mfma_f32_16x16x32_bf16(av[yy], bv, acc[yy], 0, 0, 0);
      }
    }
  }
  #pragma unroll
  for (int yy = 0; yy < 4; ++yy)
    #pragma unroll
    for (int j = 0; j < 4; ++j) {
      int r16 = kg * 4 + j;
      int y = yy * 2 + (r16 >> 3), x = r16 & 7;
      pre[((size_t)((t * 8 + n) * 8 + y) * 8 + x) * 64 + co] =
          __fadd_rn(__fmul_rn(acc[yy][j], g), bc);
    }
}

// Fused lifpool8 + FC1 (512 blocks, same parallelism as old fc1). Each block
// recomputes pool+LIF for its n into LDS (bit-identical), then fc1 exactly.
__global__ __launch_bounds__(256) void k_fc1p(
    const float* __restrict__ pre,  // [32][8][8][64] (conv4M output)
    const float* __restrict__ w, float* __restrict__ out)  // out: s1 [32][256]
{
  __shared__ float sp[1024];        // [16pp][64co] for current t

  int tid = threadIdx.x;
  int lane = tid & 63;
  int n = RFL(blockIdx.x >> 6);
  int j = ((blockIdx.x & 63) * 4 + (tid >> 6)) & 255;

  float wr[16];
  #pragma unroll
  for (int u = 0; u < 16; ++u) wr[u] = w[j * 1024 + lane * 16 + u];

  float vp[4][4];
  #pragma unroll
  for (int k = 0; k < 4; ++k)
    #pragma unroll
    for (int q = 0; q < 4; ++q) vp[k][q] = 0.f;

  float v = 0.f;   // fc1 LIF state (uniform across lanes of the wave)

  #pragma unroll 1
  for (int t = 0; t < 4; ++t) {
    #pragma unroll
    for (int k = 0; k < 4; ++k) {
      int idx = k * 256 + tid;
      int pp = idx >> 6, co = idx & 63;
      int py = pp >> 2, px = pp & 3;
      const float* pb = pre + ((size_t)((t * 8 + n) * 8 + 2 * py) * 8 + 2 * px) * 64 + co;
      float spv = fmaxf(fmaxf(lif_upd(vp[k][0], pb[0]), lif_upd(vp[k][1], pb[64])),
                        fmaxf(lif_upd(vp[k][2], pb[8 * 64]), lif_upd(vp[k][3], pb[9 * 64])));
      sp[idx] = spv;
    }
    __syncthreads();

    float sum = 0.f;
    #pragma unroll
    for (int u = 0; u < 16; ++u) sum = fmaf(wr[u], sp[u * 64 + lane], sum);
    #pragma unroll
    for (int off = 32; off > 0; off >>= 1) sum += __shfl_xor(sum, off, 64);
    float s = lif_upd(v, sum);
    if (lane == 0) out[(t * 8 + n) * 256 + j] = s;
    __syncthreads();   // before overwriting sp next t
  }
}

// FC2: (8,256)@(110,256)^T + LIF.
__global__ __launch_bounds__(256) void k_fc2(
    const float* __restrict__ s1, const float* __restrict__ w, float* __restrict__ out)
{
  int wv = blockIdx.x * 4 + (threadIdx.x >> 6);
  int lane = threadIdx.x & 63;
  int j = wv % 110;
  int n = wv / 110;
  float wr[4];
  #pragma unroll
  for (int u = 0; u < 4; ++u) wr[u] = w[j * 256 + u * 64 + lane];
  float v = 0.f;
  #pragma unroll 1
  for (int t = 0; t < 4; ++t) {
    const float* sp = s1 + (t * 8 + n) * 256;
    float sum = 0.f;
    #pragma unroll
    for (int u = 0; u < 4; ++u) sum = fmaf(wr[u], sp[u * 64 + lane], sum);
    #pragma unroll
    for (int off = 32; off > 0; off >>= 1) sum += __shfl_xor(sum, off, 64);
    float s = lif_upd(v, sum);
    if (lane == 0) out[(t * 8 + n) * 110 + j] = s;
  }
}

// acc[n][g] = sum_t mean_{j<10} s2[t][n][g*10+j]
__global__ __launch_bounds__(128) void k_acc(const float* __restrict__ s2, float* __restrict__ out) {
  int id = threadIdx.x;
  if (id >= 88) return;
  int n = id / 11, g = id % 11;
  float a = 0.f;
  #pragma unroll 1
  for (int t = 0; t < 4; ++t) {
    float m = 0.f;
    #pragma unroll
    for (int jj = 0; jj < 10; ++jj) m = __fadd_rn(m, s2[(t * 8 + n) * 110 + g * 10 + jj]);
    a = __fadd_rn(a, __fdiv_rn(m, 10.0f));
  }
  out[n * 11 + g] = a;
}

extern "C" void kernel_launch(void* const* d_in, const int* in_sizes, int n_in,
                              void* d_out, int out_size, void* d_ws, size_t ws_size,
                              hipStream_t stream)
{
  const float* x  = (const float*)d_in[0];
  const float* w0 = (const float*)d_in[1];
  const float* wc = (const float*)d_in[2];
  const float* bg = (const float*)d_in[3];
  const float* bb = (const float*)d_in[4];
  const float* bm = (const float*)d_in[5];
  const float* bv = (const float*)d_in[6];
  const float* w1 = (const float*)d_in[7];
  const float* w2 = (const float*)d_in[8];
  float* out = (float*)d_out;

  // ---- workspace layout ----
  unsigned short* sp0 = (unsigned short*)d_ws;      // [32][66][66][64]  8,921,088
  unsigned short* sp1 = sp0 + 8921088;              // [32][34][34][64]  2,367,488
  unsigned short* sp2 = sp1 + 2367488;              // [32][18][18][64]    663,552
  unsigned short* sp3 = sp2 + 663552;               // [32][10][10][64]    204,800
  unsigned short* wt  = sp3 + 204800;               // [4][3][9][4096]     442,368
  float* fbase = (float*)((char*)d_ws + 25198592);
  float* sp4  = fbase;            // (unused)          32,768
  float* pre4 = sp4 + 32768;      // [32][8][8][64]   131,072
  float* s1   = pre4 + 131072;    // [32][256]          8,192
  float* s2   = s1 + 8192;        // [32][110]          3,520
  float* padx = (float*)((char*)d_ws + 25900800);   // [32][2][130][136] 1,131,520
  if (ws_size < (size_t)30426880) return;

  constexpr int WTL = 3 * 9 * 4096;   // per-layer wt stride (ushorts)

  k_prep<<<5492, 256, 0, stream>>>(wc, wt, sp0, x, padx);

  k_conv0<<<2048, 256, 0, stream>>>(padx, w0, bg, bb, bm, bv, sp0);

  k_convT<64><<<1024, 256, 0, stream>>>(sp0, wt + 0 * WTL, bg + 64,  bb + 64,  bm + 64,  bv + 64,  sp1);
  k_convT<32><<<256, 256, 0, stream>>>(sp1, wt + 1 * WTL, bg + 128, bb + 128, bm + 128, bv + 128, sp2);
  k_convT<16><<<64, 256, 0, stream>>>(sp2, wt + 2 * WTL, bg + 192, bb + 192, bm + 192, bv + 192, sp3);

  k_conv4M<<<32, 256, 0, stream>>>(sp3, wt + 3 * WTL, bg + 256, bb + 256, bm + 256, bv + 256, pre4);

  k_fc1p<<<512, 256, 0, stream>>>(pre4, w1, s1);
  k_fc2<<<220, 256, 0, stream>>>(s1, w2, s2);
  k_acc<<<1, 128, 0, stream>>>(s2, out);
}